// Round 4
// baseline (365.674 us; speedup 1.0000x reference)
//
#include <hip/hip_runtime.h>
#include <math.h>

#define NROWS 65536
#define PER 64
#define BIMG 1024
#define NBLK 2048         // 32 rows per block
#define NCLS 36
#define OBJ_DIM 192
#define EMB 200
#define POSD 128
#define HID 1024
#define EPSV 1e-5f

#define KP 384            // padded K for GEMM1 (355 real -> 384)
#define XSTR 392          // Xs LDS row stride in fp16 units
#define GCSTR 72          // Gc row stride in fp16 units (64 + 8)
#define W2KP 1024         // W2T k stride

// X column layout (alignment-friendly; W1fT rows permuted to match):
//   [0,192)   features
//   [192,320) pos (relu(h @ pos_W + pos_b))        <- dec1_W rows 392..519
//   [320,355) distribution (folded obj_embed)      <- Fold rows 0..34
//   [355,384) zero pad

typedef __attribute__((ext_vector_type(8))) _Float16 f16x8;
typedef __attribute__((ext_vector_type(4))) _Float16 f16x4;
typedef __attribute__((ext_vector_type(4))) float f32x4;

// ---------------- fold: Fold[35][1024] = obj_embed_W(35x200) @ dec1_W[192:392](200x1024) ----
__global__ __launch_bounds__(256) void k_fold(
    const float* __restrict__ obj_embed_W, const float* __restrict__ dec1_W,
    float* __restrict__ Fold)
{
    int e = blockIdx.x;                               // 0..34
    int h = blockIdx.y * 256 + threadIdx.x;           // 0..1023
    const float* A  = obj_embed_W + (size_t)e * EMB;  // uniform -> s_load
    const float* Bp = dec1_W + (size_t)192 * HID + h;
    float acc = 0.f;
#pragma unroll 8
    for (int j = 0; j < EMB; ++j)
        acc = fmaf(A[j], Bp[(size_t)j * HID], acc);
    Fold[(size_t)e * HID + h] = acc;
}

// ---------------- prep: fused+scaled W1f^T (fp16), W2^T (fp16), bias vector ----------------
__global__ __launch_bounds__(256) void k_prep(
    const float* __restrict__ Fold, const float* __restrict__ dec1_W,
    const float* __restrict__ dec1_b,
    const float* __restrict__ bn1k_g, const float* __restrict__ bn1k_b,
    const float* __restrict__ bn1k_m, const float* __restrict__ bn1k_v,
    const float* __restrict__ dec2_W,
    _Float16* __restrict__ W1fT, _Float16* __restrict__ W2T,
    float* __restrict__ bs)
{
    int idx = blockIdx.x * 256 + threadIdx.x;
    if (idx < HID * KP) {
        int h = idx / KP, k = idx % KP;
        float sc = rsqrtf(bn1k_v[h] + EPSV) * bn1k_g[h];
        float v;
        if (k < 192)      v = dec1_W[(size_t)k * HID + h];
        else if (k < 320) v = dec1_W[(size_t)(k + 200) * HID + h];   // pos rows 392..519
        else if (k < 355) v = Fold[(size_t)(k - 320) * HID + h];     // folded obj_embed
        else              v = 0.f;
        W1fT[(size_t)h * KP + k] = (_Float16)(v * sc);
        if (k == 0) bs[h] = (dec1_b[h] - bn1k_m[h]) * sc + bn1k_b[h];
    } else {
        int j = idx - HID * KP;           // 48 * 1024 region
        if (j < 48 * W2KP) {
            int c = j / W2KP, h2 = j % W2KP;
            float v = (c < NCLS) ? dec2_W[(size_t)h2 * NCLS + c] : 0.f;
            W2T[j] = (_Float16)v;
        }
    }
}

// ---------------- main fused kernel: 32 rows/block, 4 waves, fp16 MFMA ----------------
// LDS 34304 B -> 4 blocks/CU (16 waves). Wave wv: hidden sub-block for GEMM1;
// for GEMM2: a = wv>>1 row-group, b = wv&1 k-half, partials merged via Lst.
__global__ __launch_bounds__(256, 4) void k_main(
    const float* __restrict__ distribution, const float* __restrict__ features,
    const float* __restrict__ boxes,
    const float* __restrict__ bn4_g, const float* __restrict__ bn4_b,
    const float* __restrict__ bn4_m, const float* __restrict__ bn4_v,
    const float* __restrict__ pos_W, const float* __restrict__ pos_b,
    const _Float16* __restrict__ W1fT, const _Float16* __restrict__ W2T,
    const float* __restrict__ bs, const float* __restrict__ dec2_b,
    float* __restrict__ out, float* __restrict__ Hval, float* __restrict__ Hidx)
{
    __shared__ __align__(16) char smem[34304];
    _Float16* Xs = (_Float16*)smem;                // 32*392 fp16 = 25088 B
    // Gc buffers: [25088, 29696) and [29696, 34304)
    float* Lst   = (float*)(smem + 25088);         // aliases Gc bufs (32*49*4 = 6272 B)

    int t = threadIdx.x;
    int row0 = blockIdx.x * 32;
    int wv = t >> 6, lane = t & 63, lr = lane & 15, lq = lane >> 4;
    int a = wv >> 1, b = wv & 1;

    // ---- early W2T prefetch for sub-round 0 (this wave's k-half only) ----
    f16x8 w2c[3];
#pragma unroll
    for (int n = 0; n < 3; n++)
        w2c[n] = *(const f16x8*)(W2T + (size_t)(16 * n + lr) * W2KP + 32 * b + 8 * lq);

    // ---- stage X as fp16 into Xs, all loads coalesced/vectorized ----
    {
        // features: cols [0,192). 32 rows x 48 float4 = 1536 loads, coalesced.
        const float4* F4 = (const float4*)(features + (size_t)row0 * OBJ_DIM);
#pragma unroll
        for (int it = 0; it < 6; ++it) {
            int li = t + 256 * it;                 // 0..1535
            int r = li / 48, c4 = li % 48;
            float4 v = F4[li];
            f16x4 h4;
            h4[0] = (_Float16)v.x; h4[1] = (_Float16)v.y;
            h4[2] = (_Float16)v.z; h4[3] = (_Float16)v.w;
            *(f16x4*)&Xs[r * XSTR + c4 * 4] = h4;
        }
        // distribution + zero pad: cols [320,384). 32 rows x 8 groups of 8 = 256.
        const float* D = distribution + (size_t)row0 * (NCLS - 1);
        {
            int r = t >> 3, gq = t & 7;
            f16x8 v8;
#pragma unroll
            for (int e = 0; e < 8; ++e) {
                int c = gq * 8 + e;                // 0..63
                v8[e] = (c < 35) ? (_Float16)D[(size_t)r * 35 + c] : (_Float16)0.f;
            }
            *(f16x8*)&Xs[r * XSTR + 320 + gq * 8] = v8;
        }
        // pos: cols [192,320). thread (r, kq) computes 16 cols, aligned f16x8 stores.
        int r = t >> 3, kq = t & 7;
        int grow = row0 + r;
        const float* bx = boxes + (size_t)grow * 5;
        float x1 = bx[1], y1 = bx[2], x2 = bx[3], y2 = bx[4];
        float w = x2 - x1 + 1.f, hh = y2 - y1 + 1.f;
        float cs[4] = {x1 + 0.5f * w, y1 + 0.5f * hh, w, hh};
        float hv[4];
#pragma unroll
        for (int i = 0; i < 4; i++)
            hv[i] = (cs[i] - bn4_m[i]) * rsqrtf(bn4_v[i] + EPSV) * bn4_g[i] + bn4_b[i];
#pragma unroll
        for (int jb = 0; jb < 2; ++jb) {
            int j0 = kq * 16 + jb * 8;
            f16x8 v8;
#pragma unroll
            for (int e = 0; e < 8; ++e) {
                int j = j0 + e;
                float p = pos_b[j];
                p = fmaf(hv[0], pos_W[j], p);
                p = fmaf(hv[1], pos_W[POSD + j], p);
                p = fmaf(hv[2], pos_W[2 * POSD + j], p);
                p = fmaf(hv[3], pos_W[3 * POSD + j], p);
                v8[e] = (_Float16)fmaxf(p, 0.f);
            }
            *(f16x8*)&Xs[r * XSTR + 192 + j0] = v8;
        }
    }
    __syncthreads();

    f32x4 Lg[3];                       // partial logit frags (rows 16a.., k-half b)
#pragma unroll
    for (int n = 0; n < 3; n++) Lg[n] = (f32x4){0.f, 0.f, 0.f, 0.f};

    for (int c0 = 0; c0 < 4; ++c0) {   // hidden chunks of 256
        int H0 = c0 * 256;
        const _Float16* wp = W1fT + (size_t)(H0 + 16 * wv + lr) * KP;

        f32x4 bsv4[4];
#pragma unroll
        for (int j = 0; j < 4; j++)
            bsv4[j] = *(const f32x4*)(bs + H0 + 16 * (wv + 4 * j) + 4 * lq);

        f32x4 C[4][2];
#pragma unroll
        for (int j = 0; j < 4; j++)
#pragma unroll
            for (int n = 0; n < 2; n++) C[j][n] = (f32x4){0.f, 0.f, 0.f, 0.f};

        // ---- GEMM1 K-loop: depth-1 register prefetch ----
        f16x8 ahc[4], bhc[2];
        {
            int k0 = lq * 8;
#pragma unroll
            for (int j2 = 0; j2 < 4; j2++) ahc[j2] = *(const f16x8*)(wp + (size_t)(64 * j2) * KP + k0);
#pragma unroll
            for (int n = 0; n < 2; n++) bhc[n] = *(const f16x8*)&Xs[(16 * n + lr) * XSTR + k0];
        }
#pragma unroll
        for (int ks = 0; ks < 11; ++ks) {
            f16x8 ahn[4], bhn[2];
            int k1 = (ks + 1) * 32 + lq * 8;
#pragma unroll
            for (int j2 = 0; j2 < 4; j2++) ahn[j2] = *(const f16x8*)(wp + (size_t)(64 * j2) * KP + k1);
#pragma unroll
            for (int n = 0; n < 2; n++) bhn[n] = *(const f16x8*)&Xs[(16 * n + lr) * XSTR + k1];
#pragma unroll
            for (int j2 = 0; j2 < 4; j2++)
#pragma unroll
                for (int n = 0; n < 2; n++)
                    C[j2][n] = __builtin_amdgcn_mfma_f32_16x16x32_f16(ahc[j2], bhc[n], C[j2][n], 0, 0, 0);
#pragma unroll
            for (int j2 = 0; j2 < 4; j2++) ahc[j2] = ahn[j2];
#pragma unroll
            for (int n = 0; n < 2; n++) bhc[n] = bhn[n];
        }
#pragma unroll
        for (int j2 = 0; j2 < 4; j2++)
#pragma unroll
            for (int n = 0; n < 2; n++)
                C[j2][n] = __builtin_amdgcn_mfma_f32_16x16x32_f16(ahc[j2], bhc[n], C[j2][n], 0, 0, 0);

        // ---- transform + GEMM2, 4 sub-rounds of 64 hidden, double-buffered Gc ----
#pragma unroll
        for (int j = 0; j < 4; ++j) {
            _Float16* Gcb = (_Float16*)(smem + 25088 + 4608 * (j & 1));
#pragma unroll
            for (int n = 0; n < 2; n++) {
                f16x4 g4;
#pragma unroll
                for (int e = 0; e < 4; ++e)
                    g4[e] = (_Float16)fmaxf(C[j][n][e] + bsv4[j][e], 0.f);
                *(f16x4*)&Gcb[(16 * n + lr) * GCSTR + 16 * wv + 4 * lq] = g4;
            }
            __syncthreads();           // Gc[buf] filled (prior reads were 2 sub-rounds back)
            f16x8 a2 = *(const f16x8*)&Gcb[(16 * a + lr) * GCSTR + 32 * b + 8 * lq];
            int s = c0 * 4 + j;
            int hgn = (s < 15) ? 64 * (s + 1) : 0;
            f16x8 w2n[3];
#pragma unroll
            for (int n = 0; n < 3; n++)
                w2n[n] = *(const f16x8*)(W2T + (size_t)(16 * n + lr) * W2KP + hgn + 32 * b + 8 * lq);
#pragma unroll
            for (int n = 0; n < 3; n++)
                Lg[n] = __builtin_amdgcn_mfma_f32_16x16x32_f16(a2, w2c[n], Lg[n], 0, 0, 0);
#pragma unroll
            for (int n = 0; n < 3; n++) w2c[n] = w2n[n];
        }
    }

    __syncthreads();                   // all Gc reads done; region becomes logit stash
    // merge k-half partials: b=1 writes, b=0 adds.
    if (b == 1) {
#pragma unroll
        for (int n = 0; n < 3; n++)
#pragma unroll
            for (int e = 0; e < 4; ++e)
                Lst[(16 * a + 4 * lq + e) * 49 + 16 * n + lr] = Lg[n][e];
    }
    __syncthreads();
    if (b == 0) {
#pragma unroll
        for (int n = 0; n < 3; n++)
#pragma unroll
            for (int e = 0; e < 4; ++e)
                Lst[(16 * a + 4 * lq + e) * 49 + 16 * n + lr] += Lg[n][e];
    }
    __syncthreads();

    // ---- softmax head; per-block (32-row) human candidate to ws ----
    if (t < 32) {
        int row = row0 + t;
        float lg[36];
#pragma unroll
        for (int c = 1; c < 36; ++c) lg[c] = Lst[t * 49 + c] + dec2_b[c];
        float m = lg[1];
#pragma unroll
        for (int c = 2; c < 36; ++c) m = fmaxf(m, lg[c]);
        float d[35];
        float s = 0.f;
#pragma unroll
        for (int c = 1; c < 36; ++c) { float e = expf(lg[c] - m); d[c - 1] = e; s += e; }
        float inv = 1.0f / s;
        float* dout = out + (size_t)row * 35;
#pragma unroll
        for (int j = 0; j < 35; ++j) dout[j] = d[j] * inv;

        // per-row argmax over dist cols 1..34 (first-occurrence), label = distcol+1
        float best = -1.f; int bi = 1;
#pragma unroll
        for (int c = 1; c < 35; ++c) {
            float v = d[c] * inv;
            if (v > best) { best = v; bi = c; }
        }
        // non-human values for every row; k_fix overwrites the one human row.
        out[(size_t)NROWS * 35 + row] = best;
        out[(size_t)NROWS * 36 + row] = (float)(bi + 1);

        // 32-lane reduce: group winner of dist[:,0] (first-occurrence on ties)
        float v0 = d[0] * inv;
        float mv = v0; int mi = t;
#pragma unroll
        for (int off = 16; off > 0; off >>= 1) {
            float ov = __shfl_down(mv, off);
            int   oi = __shfl_down(mi, off);
            if (ov > mv || (ov == mv && oi < mi)) { mv = ov; mi = oi; }
        }
        if (t == 0) { Hval[blockIdx.x] = mv; Hidx[blockIdx.x] = (float)mi; }
    }
}

// ---------------- fixup: resolve per-image human across the 2 row-groups ----------------
__global__ __launch_bounds__(256) void k_fix(
    const float* __restrict__ Hval, const float* __restrict__ Hidx,
    float* __restrict__ out)
{
    int i = blockIdx.x * 256 + threadIdx.x;
    if (i < BIMG) {
        float v0 = Hval[2 * i], v1 = Hval[2 * i + 1];
        int i0 = (int)Hidx[2 * i], i1 = (int)Hidx[2 * i + 1];
        bool g1 = (v1 > v0);                        // ties -> group 0 (first occurrence)
        int h = g1 ? (64 * i + 32 + i1) : (64 * i + i0);
        float vh = g1 ? v1 : v0;
        out[(size_t)NROWS * 35 + h] = vh;
        out[(size_t)NROWS * 36 + h] = 1.0f;
        out[(size_t)NROWS * 37 + i] = (float)h;
    }
}

extern "C" void kernel_launch(void* const* d_in, const int* in_sizes, int n_in,
                              void* d_out, int out_size, void* d_ws, size_t ws_size,
                              hipStream_t stream)
{
    (void)in_sizes; (void)n_in; (void)out_size; (void)ws_size;
    const float* distribution = (const float*)d_in[0];
    const float* features     = (const float*)d_in[1];
    const float* boxes        = (const float*)d_in[2];
    const float* obj_embed_W  = (const float*)d_in[3];
    const float* bn4_g        = (const float*)d_in[4];
    const float* bn4_b        = (const float*)d_in[5];
    const float* bn4_m        = (const float*)d_in[6];
    const float* bn4_v        = (const float*)d_in[7];
    const float* pos_W        = (const float*)d_in[8];
    const float* pos_b        = (const float*)d_in[9];
    const float* dec1_W       = (const float*)d_in[10];
    const float* dec1_b       = (const float*)d_in[11];
    const float* bn1k_g       = (const float*)d_in[12];
    const float* bn1k_b       = (const float*)d_in[13];
    const float* bn1k_m       = (const float*)d_in[14];
    const float* bn1k_v       = (const float*)d_in[15];
    const float* dec2_W       = (const float*)d_in[16];
    const float* dec2_b       = (const float*)d_in[17];

    float* out = (float*)d_out;

    // ws layout (~1.06 MB)
    _Float16* W1fT = (_Float16*)d_ws;                      // 1024*384 fp16
    _Float16* W2T  = W1fT + (size_t)HID * KP;              // 48*1024 fp16
    float*    bsv  = (float*)(W2T + (size_t)48 * W2KP);    // 1024 f32
    float*    Fold = bsv + HID;                            // 35*1024 f32
    float*    Hval = Fold + (size_t)35 * HID;              // 2048 f32
    float*    Hidx = Hval + NBLK;                          // 2048 f32

    k_fold<<<dim3(35, 4), 256, 0, stream>>>(obj_embed_W, dec1_W, Fold);

    int prep_elems = HID * KP + 48 * W2KP;
    k_prep<<<(prep_elems + 255) / 256, 256, 0, stream>>>(
        Fold, dec1_W, dec1_b, bn1k_g, bn1k_b, bn1k_m, bn1k_v, dec2_W,
        W1fT, W2T, bsv);

    k_main<<<NBLK, 256, 0, stream>>>(
        distribution, features, boxes, bn4_g, bn4_b, bn4_m, bn4_v, pos_W, pos_b,
        W1fT, W2T, bsv, dec2_b, out, Hval, Hidx);

    k_fix<<<(BIMG + 255) / 256, 256, 0, stream>>>(Hval, Hidx, out);
}

// Round 6
// 268.033 us; speedup vs baseline: 1.3643x; 1.3643x over previous
//
#include <hip/hip_runtime.h>
#include <math.h>

#define NROWS 65536
#define PER 64
#define BIMG 1024
#define NCLS 36
#define OBJ_DIM 192
#define EMB 200
#define POSD 128
#define HID 1024
#define EPSV 1e-5f

#define KP 384            // padded K for GEMM1 (355 real -> 384)
#define XSTR 392          // Xs LDS row stride in fp16 units
#define GCSTR 72          // Gc row stride in fp16 units (64 + 8)

// X column layout (alignment-friendly; W1 packing permuted to match):
//   [0,192)   features
//   [192,320) pos (relu(h @ pos_W + pos_b))        <- dec1_W rows 392..519
//   [320,355) distribution (folded obj_embed)      <- Fold rows 0..34
//   [355,384) zero pad
//
// W1p fragment-packed layout: idx = ((ht*12 + ks)*64 + lane)*8 + e
//   h = 16*ht + (lane&15), k = 32*ks + 8*(lane>>4) + e
//   -> one wave A-fragment load = 64 lanes x 16B CONTIGUOUS (8 full 128B lines)
// W2p fragment-packed layout: idx = ((n*32 + s2)*64 + lane)*8 + e
//   class c = 16*n + (lane&15), hidden = 32*s2 + 8*(lane>>4) + e

typedef __attribute__((ext_vector_type(8))) _Float16 f16x8;
typedef __attribute__((ext_vector_type(4))) _Float16 f16x4;
typedef __attribute__((ext_vector_type(4))) float f32x4;

// ---------------- fold: Fold[35][1024] = obj_embed_W(35x200) @ dec1_W[192:392](200x1024) ----
__global__ __launch_bounds__(256) void k_fold(
    const float* __restrict__ obj_embed_W, const float* __restrict__ dec1_W,
    float* __restrict__ Fold)
{
    int e = blockIdx.x;                               // 0..34
    int h = blockIdx.y * 256 + threadIdx.x;           // 0..1023
    const float* A  = obj_embed_W + (size_t)e * EMB;  // uniform -> s_load
    const float* Bp = dec1_W + (size_t)192 * HID + h;
    float acc = 0.f;
#pragma unroll 8
    for (int j = 0; j < EMB; ++j)
        acc = fmaf(A[j], Bp[(size_t)j * HID], acc);
    Fold[(size_t)e * HID + h] = acc;
}

// ---------------- prep: fragment-packed scaled W1p (fp16), W2p (fp16), bias vector ----------
__global__ __launch_bounds__(256) void k_prep(
    const float* __restrict__ Fold, const float* __restrict__ dec1_W,
    const float* __restrict__ dec1_b,
    const float* __restrict__ bn1k_g, const float* __restrict__ bn1k_b,
    const float* __restrict__ bn1k_m, const float* __restrict__ bn1k_v,
    const float* __restrict__ dec2_W,
    _Float16* __restrict__ W1p, _Float16* __restrict__ W2p,
    float* __restrict__ bs)
{
    int idx = blockIdx.x * 256 + threadIdx.x;
    if (idx < HID * KP) {
        int e  = idx & 7;
        int l  = (idx >> 3) & 63;
        int ks = (idx >> 9) % 12;
        int ht = idx / 6144;
        int h = ht * 16 + (l & 15);
        int k = ks * 32 + (l >> 4) * 8 + e;
        float sc = rsqrtf(bn1k_v[h] + EPSV) * bn1k_g[h];
        float v;
        if (k < 192)      v = dec1_W[(size_t)k * HID + h];
        else if (k < 320) v = dec1_W[(size_t)(k + 200) * HID + h];   // pos rows 392..519
        else if (k < 355) v = Fold[(size_t)(k - 320) * HID + h];     // folded obj_embed
        else              v = 0.f;
        W1p[idx] = (_Float16)(v * sc);
        if (k == 0) bs[h] = (dec1_b[h] - bn1k_m[h]) * sc + bn1k_b[h];  // once per h
    } else {
        int p2 = idx - HID * KP;
        if (p2 < 3 * 32 * 512) {
            int e  = p2 & 7;
            int l  = (p2 >> 3) & 63;
            int s2 = (p2 >> 9) & 31;
            int n  = p2 / 16384;
            int c  = n * 16 + (l & 15);
            int hd = s2 * 32 + (l >> 4) * 8 + e;
            W2p[p2] = (_Float16)((c < NCLS) ? dec2_W[(size_t)hd * NCLS + c] : 0.f);
        }
    }
}

// ---------------- main fused kernel: 64 rows/block, 4 waves, 128h x 64r per-wave tile ------
__global__ __launch_bounds__(256, 2) void k_main(
    const float* __restrict__ distribution, const float* __restrict__ features,
    const float* __restrict__ boxes,
    const float* __restrict__ bn4_g, const float* __restrict__ bn4_b,
    const float* __restrict__ bn4_m, const float* __restrict__ bn4_v,
    const float* __restrict__ pos_W, const float* __restrict__ pos_b,
    const _Float16* __restrict__ W1p, const _Float16* __restrict__ W2p,
    const float* __restrict__ bs, const float* __restrict__ dec2_b,
    float* __restrict__ out)
{
    __shared__ __align__(16) char smem[68608];
    _Float16* Xs = (_Float16*)smem;                // 64*392 fp16 = 50176 B
    // Gc buffers: [50176, 59392) and [59392, 68608)
    float* Lst   = (float*)(smem + 50176);         // aliases Gc bufs (64*49*4 = 12544 B)

    int t = threadIdx.x;
    int row0 = blockIdx.x * PER;
    int wv = t >> 6, lane = t & 63, lr = lane & 15, lq = lane >> 4;

    // ---- stage X as fp16 into Xs, all loads coalesced/vectorized ----
    {
        // features: cols [0,192). 64 rows x 48 float4, fully coalesced, non-temporal.
        const f32x4* F4 = (const f32x4*)(features + (size_t)row0 * OBJ_DIM);
#pragma unroll
        for (int it = 0; it < 12; ++it) {
            int li = t + 256 * it;                 // 0..3071
            int r = li / 48, c4 = li % 48;
            f32x4 v = __builtin_nontemporal_load(F4 + li);
            f16x4 h4;
            h4[0] = (_Float16)v[0]; h4[1] = (_Float16)v[1];
            h4[2] = (_Float16)v[2]; h4[3] = (_Float16)v[3];
            *(f16x4*)&Xs[r * XSTR + c4 * 4] = h4;
        }
        // distribution + zero pad: cols [320,384). 64 rows x 8 groups of 8.
        const float* D = distribution + (size_t)row0 * (NCLS - 1);
#pragma unroll
        for (int it = 0; it < 2; ++it) {
            int li = t + 256 * it;                 // 0..511
            int r = li >> 3, gq = li & 7;
            f16x8 v8;
#pragma unroll
            for (int e = 0; e < 8; ++e) {
                int c = gq * 8 + e;                // 0..63
                v8[e] = (c < 35) ? (_Float16)__builtin_nontemporal_load(D + (size_t)r * 35 + c)
                                 : (_Float16)0.f;
            }
            *(f16x8*)&Xs[r * XSTR + 320 + gq * 8] = v8;
        }
        // pos: cols [192,320). thread (r, kq) computes 32 cols, aligned f16x8 stores.
        int r = t >> 2, kq = t & 3;
        int grow = row0 + r;
        const float* bx = boxes + (size_t)grow * 5;
        float x1 = bx[1], y1 = bx[2], x2 = bx[3], y2 = bx[4];
        float w = x2 - x1 + 1.f, hh = y2 - y1 + 1.f;
        float cs[4] = {x1 + 0.5f * w, y1 + 0.5f * hh, w, hh};
        float hv[4];
#pragma unroll
        for (int i = 0; i < 4; i++)
            hv[i] = (cs[i] - bn4_m[i]) * rsqrtf(bn4_v[i] + EPSV) * bn4_g[i] + bn4_b[i];
#pragma unroll
        for (int jb = 0; jb < 4; ++jb) {
            int j0 = kq * 32 + jb * 8;
            f16x8 v8;
#pragma unroll
            for (int e = 0; e < 8; ++e) {
                int j = j0 + e;
                float p = pos_b[j];
                p = fmaf(hv[0], pos_W[j], p);
                p = fmaf(hv[1], pos_W[POSD + j], p);
                p = fmaf(hv[2], pos_W[2 * POSD + j], p);
                p = fmaf(hv[3], pos_W[3 * POSD + j], p);
                v8[e] = (_Float16)fmaxf(p, 0.f);
            }
            *(f16x8*)&Xs[r * XSTR + 192 + j0] = v8;
        }
    }
    __syncthreads();

    f32x4 Lg[3];                       // logit frags: rows 16wv..+15 x classes 48
#pragma unroll
    for (int n = 0; n < 3; n++) Lg[n] = (f32x4){0.f, 0.f, 0.f, 0.f};

    for (int c0 = 0; c0 < 2; ++c0) {   // hidden chunks of 512
        int H0 = 512 * c0;
        // this wave's packed A base: ht0 = 32*c0 + wv (h-blocks wv, wv+4, ..., wv+28 within chunk)
        const _Float16* ap = W1p + ((size_t)(32 * c0 + wv) * 12) * 512 + (size_t)lane * 8;

        f32x4 C[8][4];
#pragma unroll
        for (int j = 0; j < 8; j++)
#pragma unroll
            for (int n = 0; n < 4; n++) C[j][n] = (f32x4){0.f, 0.f, 0.f, 0.f};

        // ---- GEMM1 K-loop: 12 loads / 32 MFMA per step; A-loads lane-contiguous ----
#pragma unroll 4
        for (int ks = 0; ks < 12; ++ks) {
            f16x8 ah[8], bh[4];
#pragma unroll
            for (int j = 0; j < 8; j++)
                ah[j] = *(const f16x8*)(ap + ((size_t)(4 * j) * 12 + ks) * 512);
#pragma unroll
            for (int n = 0; n < 4; n++)
                bh[n] = *(const f16x8*)&Xs[(16 * n + lr) * XSTR + ks * 32 + lq * 8];
#pragma unroll
            for (int j = 0; j < 8; j++)
#pragma unroll
                for (int n = 0; n < 4; n++)
                    C[j][n] = __builtin_amdgcn_mfma_f32_16x16x32_f16(ah[j], bh[n], C[j][n], 0, 0, 0);
        }

        // ---- transform + GEMM2, 8 sub-rounds of 64 hidden, double-buffered Gc ----
#pragma unroll
        for (int j = 0; j < 8; ++j) {
            _Float16* Gcb = (_Float16*)(smem + 50176 + 9216 * (j & 1));
            f32x4 bsv = *(const f32x4*)(bs + H0 + 16 * (wv + 4 * j) + 4 * lq);
#pragma unroll
            for (int n = 0; n < 4; n++) {
                f16x4 g4;
#pragma unroll
                for (int e = 0; e < 4; ++e)
                    g4[e] = (_Float16)fmaxf(C[j][n][e] + bsv[e], 0.f);
                *(f16x4*)&Gcb[(16 * n + lr) * GCSTR + 16 * wv + 4 * lq] = g4;
            }
            __syncthreads();           // Gc[buf] filled (prior reads of this buf were 2 rounds back)
            int s = 8 * c0 + j;        // global sub-round 0..15
            f16x8 b2[3][2];
#pragma unroll
            for (int n = 0; n < 3; n++)
#pragma unroll
                for (int ks2 = 0; ks2 < 2; ks2++)
                    b2[n][ks2] = *(const f16x8*)(W2p + ((size_t)(n * 32 + 2 * s + ks2) * 64 + lane) * 8);
            f16x8 a2[2];
#pragma unroll
            for (int ks2 = 0; ks2 < 2; ks2++)
                a2[ks2] = *(const f16x8*)&Gcb[(16 * wv + lr) * GCSTR + 32 * ks2 + 8 * lq];
#pragma unroll
            for (int ks2 = 0; ks2 < 2; ks2++)
#pragma unroll
                for (int n = 0; n < 3; n++)
                    Lg[n] = __builtin_amdgcn_mfma_f32_16x16x32_f16(a2[ks2], b2[n][ks2], Lg[n], 0, 0, 0);
        }
    }

    __syncthreads();                   // last GEMM2 reads done; Gc region becomes logit stash
#pragma unroll
    for (int n = 0; n < 3; n++)
#pragma unroll
        for (int e = 0; e < 4; ++e)
            Lst[(16 * wv + 4 * lq + e) * 49 + 16 * n + lr] = Lg[n][e];
    __syncthreads();

    // ---- softmax head + fused per-image human argmax (t<64 == wave 0) ----
    if (t < 64) {
        int row = row0 + t;
        float lg[36];
#pragma unroll
        for (int c = 1; c < 36; ++c) lg[c] = Lst[t * 49 + c] + dec2_b[c];
        float m = lg[1];
#pragma unroll
        for (int c = 2; c < 36; ++c) m = fmaxf(m, lg[c]);
        float d[35];
        float s = 0.f;
#pragma unroll
        for (int c = 1; c < 36; ++c) { float e = expf(lg[c] - m); d[c - 1] = e; s += e; }
        float inv = 1.0f / s;
        float* dout = out + (size_t)row * 35;
#pragma unroll
        for (int j = 0; j < 35; ++j) dout[j] = d[j] * inv;

        // per-row argmax over dist cols 1..34 (first-occurrence), label = distcol+1
        float best = -1.f; int bi = 1;
#pragma unroll
        for (int c = 1; c < 35; ++c) {
            float v = d[c] * inv;
            if (v > best) { best = v; bi = c; }
        }

        // block == image: argmax over dist[:,0] across the 64 lanes
        float v0 = d[0] * inv;
        float mv = v0; int mi = t;
#pragma unroll
        for (int off = 32; off > 0; off >>= 1) {
            float ov = __shfl_down(mv, off);
            int   oi = __shfl_down(mi, off);
            if (ov > mv || (ov == mv && oi < mi)) { mv = ov; mi = oi; }
        }
        int human = __shfl(mi, 0);     // local row of the human
        bool isH = (t == human);
        out[(size_t)NROWS * 35 + row] = isH ? v0 : best;
        out[(size_t)NROWS * 36 + row] = isH ? 1.0f : (float)(bi + 1);
        if (t == 0) out[(size_t)NROWS * 37 + blockIdx.x] = (float)(row0 + human);
    }
}

extern "C" void kernel_launch(void* const* d_in, const int* in_sizes, int n_in,
                              void* d_out, int out_size, void* d_ws, size_t ws_size,
                              hipStream_t stream)
{
    (void)in_sizes; (void)n_in; (void)out_size; (void)ws_size;
    const float* distribution = (const float*)d_in[0];
    const float* features     = (const float*)d_in[1];
    const float* boxes        = (const float*)d_in[2];
    const float* obj_embed_W  = (const float*)d_in[3];
    const float* bn4_g        = (const float*)d_in[4];
    const float* bn4_b        = (const float*)d_in[5];
    const float* bn4_m        = (const float*)d_in[6];
    const float* bn4_v        = (const float*)d_in[7];
    const float* pos_W        = (const float*)d_in[8];
    const float* pos_b        = (const float*)d_in[9];
    const float* dec1_W       = (const float*)d_in[10];
    const float* dec1_b       = (const float*)d_in[11];
    const float* bn1k_g       = (const float*)d_in[12];
    const float* bn1k_b       = (const float*)d_in[13];
    const float* bn1k_m       = (const float*)d_in[14];
    const float* bn1k_v       = (const float*)d_in[15];
    const float* dec2_W       = (const float*)d_in[16];
    const float* dec2_b       = (const float*)d_in[17];

    float* out = (float*)d_out;

    // ws layout (~1.01 MB)
    _Float16* W1p  = (_Float16*)d_ws;                      // 1024*384 fp16 (fragment-packed)
    _Float16* W2p  = W1p + (size_t)HID * KP;               // 3*32*512 fp16 (fragment-packed)
    float*    bsv  = (float*)(W2p + (size_t)3 * 32 * 512); // 1024 f32
    float*    Fold = bsv + HID;                            // 35*1024 f32

    k_fold<<<dim3(35, 4), 256, 0, stream>>>(obj_embed_W, dec1_W, Fold);

    int prep_elems = HID * KP + 3 * 32 * 512;              // 442368
    k_prep<<<(prep_elems + 255) / 256, 256, 0, stream>>>(
        Fold, dec1_W, dec1_b, bn1k_g, bn1k_b, bn1k_m, bn1k_v, dec2_W,
        W1p, W2p, bsv);

    k_main<<<BIMG, 256, 0, stream>>>(
        distribution, features, boxes, bn4_g, bn4_b, bn4_m, bn4_v, pos_W, pos_b,
        W1p, W2p, bsv, dec2_b, out);
}

// Round 7
// 226.712 us; speedup vs baseline: 1.6129x; 1.1823x over previous
//
#include <hip/hip_runtime.h>
#include <math.h>

#define NROWS 65536
#define PER 64
#define BIMG 1024
#define NCLS 36
#define OBJ_DIM 192
#define EMB 200
#define POSD 128
#define HID 1024
#define EPSV 1e-5f

#define KP 384            // padded K for GEMM1 (355 real -> 384)
#define XSTR 392          // Xs LDS row stride in fp16 units
#define LSTR 52           // Lst row stride in floats (bank-friendly: 4*52 % 32 == 16)

// X column layout (alignment-friendly; W1 packing permuted to match):
//   [0,192)   features
//   [192,320) pos (relu(h @ pos_W + pos_b))        <- dec1_W rows 392..519
//   [320,355) distribution (folded obj_embed)      <- Fold rows 0..34
//   [355,384) zero pad
//
// W1p fragment-packed layout: idx = ((ht*12 + ks)*64 + lane)*8 + e
//   h = 16*ht + (lane&15), k = 32*ks + 8*(lane>>4) + e
// W2p fragment-packed for mfma_16x16x16f16 B-operand:
//   idx = ((ht*3 + cls)*64 + lane)*4 + e
//   c = 16*cls + (lane&15), h = 16*ht + 4*(lane>>4) + e
//
// GEMM2 is IN-REGISTER: GEMM1 C-fragment layout (lane: r=16n+lr, h_local=4lq+e)
// is exactly the mfma_16x16x16f16 A-operand layout -> no LDS round-trip, no
// per-sub-round barriers. Partial logits merged once at the end via Lst.

typedef __attribute__((ext_vector_type(8))) _Float16 f16x8;
typedef __attribute__((ext_vector_type(4))) _Float16 f16x4;
typedef __attribute__((ext_vector_type(4))) float f32x4;

// ---------------- fold: Fold[35][1024] = obj_embed_W(35x200) @ dec1_W[192:392](200x1024) ----
__global__ __launch_bounds__(256) void k_fold(
    const float* __restrict__ obj_embed_W, const float* __restrict__ dec1_W,
    float* __restrict__ Fold)
{
    int e = blockIdx.x;                               // 0..34
    int h = blockIdx.y * 256 + threadIdx.x;           // 0..1023
    const float* A  = obj_embed_W + (size_t)e * EMB;  // uniform -> s_load
    const float* Bp = dec1_W + (size_t)192 * HID + h;
    float acc = 0.f;
#pragma unroll 8
    for (int j = 0; j < EMB; ++j)
        acc = fmaf(A[j], Bp[(size_t)j * HID], acc);
    Fold[(size_t)e * HID + h] = acc;
}

// ---------------- prep: fragment-packed scaled W1p (fp16), W2p (fp16), bias vector ----------
__global__ __launch_bounds__(256) void k_prep(
    const float* __restrict__ Fold, const float* __restrict__ dec1_W,
    const float* __restrict__ dec1_b,
    const float* __restrict__ bn1k_g, const float* __restrict__ bn1k_b,
    const float* __restrict__ bn1k_m, const float* __restrict__ bn1k_v,
    const float* __restrict__ dec2_W,
    _Float16* __restrict__ W1p, _Float16* __restrict__ W2p,
    float* __restrict__ bs)
{
    int idx = blockIdx.x * 256 + threadIdx.x;
    if (idx < HID * KP) {
        int e  = idx & 7;
        int l  = (idx >> 3) & 63;
        int ks = (idx >> 9) % 12;
        int ht = idx / 6144;
        int h = ht * 16 + (l & 15);
        int k = ks * 32 + (l >> 4) * 8 + e;
        float sc = rsqrtf(bn1k_v[h] + EPSV) * bn1k_g[h];
        float v;
        if (k < 192)      v = dec1_W[(size_t)k * HID + h];
        else if (k < 320) v = dec1_W[(size_t)(k + 200) * HID + h];   // pos rows 392..519
        else if (k < 355) v = Fold[(size_t)(k - 320) * HID + h];     // folded obj_embed
        else              v = 0.f;
        W1p[idx] = (_Float16)(v * sc);
        if (k == 0) bs[h] = (dec1_b[h] - bn1k_m[h]) * sc + bn1k_b[h];  // once per h
    } else {
        int p2 = idx - HID * KP;
        if (p2 < 64 * 3 * 256) {          // 49152
            int e   = p2 & 3;
            int l   = (p2 >> 2) & 63;
            int cls = (p2 >> 8) % 3;
            int ht  = p2 / 768;
            int h = 16 * ht + 4 * (l >> 4) + e;
            int c = 16 * cls + (l & 15);
            W2p[p2] = (c < NCLS) ? (_Float16)dec2_W[(size_t)h * NCLS + c] : (_Float16)0.f;
        }
    }
}

// ---------------- main fused kernel: 64 rows/block, 4 waves, barrier-free GEMM2 ------------
__global__ __launch_bounds__(256, 2) void k_main(
    const float* __restrict__ distribution, const float* __restrict__ features,
    const float* __restrict__ boxes,
    const float* __restrict__ bn4_g, const float* __restrict__ bn4_b,
    const float* __restrict__ bn4_m, const float* __restrict__ bn4_v,
    const float* __restrict__ pos_W, const float* __restrict__ pos_b,
    const _Float16* __restrict__ W1p, const _Float16* __restrict__ W2p,
    const float* __restrict__ bs, const float* __restrict__ dec2_b,
    float* __restrict__ out)
{
    __shared__ __align__(16) char smem[53248];
    _Float16* Xs = (_Float16*)smem;                // 64*392 fp16 = 50176 B
    float* Lst   = (float*)smem;                   // aliases Xs AFTER compute: 4*64*52*4 = 53248 B

    int t = threadIdx.x;
    int row0 = blockIdx.x * PER;
    int wv = t >> 6, lane = t & 63, lr = lane & 15, lq = lane >> 4;

    // ---- stage X as fp16 into Xs, all loads coalesced/vectorized ----
    {
        // features: cols [0,192). 64 rows x 48 float4, fully coalesced, non-temporal.
        const f32x4* F4 = (const f32x4*)(features + (size_t)row0 * OBJ_DIM);
#pragma unroll
        for (int it = 0; it < 12; ++it) {
            int li = t + 256 * it;                 // 0..3071
            int r = li / 48, c4 = li % 48;
            f32x4 v = __builtin_nontemporal_load(F4 + li);
            f16x4 h4;
            h4[0] = (_Float16)v[0]; h4[1] = (_Float16)v[1];
            h4[2] = (_Float16)v[2]; h4[3] = (_Float16)v[3];
            *(f16x4*)&Xs[r * XSTR + c4 * 4] = h4;
        }
        // distribution + zero pad: cols [320,384). 64 rows x 8 groups of 8.
        const float* D = distribution + (size_t)row0 * (NCLS - 1);
#pragma unroll
        for (int it = 0; it < 2; ++it) {
            int li = t + 256 * it;                 // 0..511
            int r = li >> 3, gq = li & 7;
            f16x8 v8;
#pragma unroll
            for (int e = 0; e < 8; ++e) {
                int c = gq * 8 + e;                // 0..63
                v8[e] = (c < 35) ? (_Float16)__builtin_nontemporal_load(D + (size_t)r * 35 + c)
                                 : (_Float16)0.f;
            }
            *(f16x8*)&Xs[r * XSTR + 320 + gq * 8] = v8;
        }
        // pos: cols [192,320). thread (r, kq) computes 32 cols, aligned f16x8 stores.
        int r = t >> 2, kq = t & 3;
        int grow = row0 + r;
        const float* bx = boxes + (size_t)grow * 5;
        float x1 = bx[1], y1 = bx[2], x2 = bx[3], y2 = bx[4];
        float w = x2 - x1 + 1.f, hh = y2 - y1 + 1.f;
        float cs[4] = {x1 + 0.5f * w, y1 + 0.5f * hh, w, hh};
        float hv[4];
#pragma unroll
        for (int i = 0; i < 4; i++)
            hv[i] = (cs[i] - bn4_m[i]) * rsqrtf(bn4_v[i] + EPSV) * bn4_g[i] + bn4_b[i];
#pragma unroll
        for (int jb = 0; jb < 4; ++jb) {
            int j0 = kq * 32 + jb * 8;
            f16x8 v8;
#pragma unroll
            for (int e = 0; e < 8; ++e) {
                int j = j0 + e;
                float p = pos_b[j];
                p = fmaf(hv[0], pos_W[j], p);
                p = fmaf(hv[1], pos_W[POSD + j], p);
                p = fmaf(hv[2], pos_W[2 * POSD + j], p);
                p = fmaf(hv[3], pos_W[3 * POSD + j], p);
                v8[e] = (_Float16)fmaxf(p, 0.f);
            }
            *(f16x8*)&Xs[r * XSTR + 192 + j0] = v8;
        }
    }
    __syncthreads();                   // barrier 1 of 3

    f32x4 Lg[4][3];                    // partial logits over this wave's h-slice:
#pragma unroll                         // lane: r = 16n + 4lq+e, c = 16cls + lr
    for (int n = 0; n < 4; n++)
#pragma unroll
        for (int cls = 0; cls < 3; cls++) Lg[n][cls] = (f32x4){0.f, 0.f, 0.f, 0.f};

    for (int c0 = 0; c0 < 4; ++c0) {   // hidden chunks of 256
        // wave's packed A base: ht = 16*c0 + wv + 4*j
        const _Float16* ap = W1p + ((size_t)(16 * c0 + wv) * 12) * 512 + (size_t)lane * 8;

        f32x4 C[4][4];
#pragma unroll
        for (int j = 0; j < 4; j++)
#pragma unroll
            for (int n = 0; n < 4; n++) C[j][n] = (f32x4){0.f, 0.f, 0.f, 0.f};

        // ---- GEMM1 K-loop: 8 loads / 16 MFMA per step; A-loads lane-contiguous ----
#pragma unroll 4
        for (int ks = 0; ks < 12; ++ks) {
            f16x8 ah[4], bh[4];
#pragma unroll
            for (int j = 0; j < 4; j++)
                ah[j] = *(const f16x8*)(ap + ((size_t)(4 * j) * 12 + ks) * 512);
#pragma unroll
            for (int n = 0; n < 4; n++)
                bh[n] = *(const f16x8*)&Xs[(16 * n + lr) * XSTR + ks * 32 + lq * 8];
#pragma unroll
            for (int j = 0; j < 4; j++)
#pragma unroll
                for (int n = 0; n < 4; n++)
                    C[j][n] = __builtin_amdgcn_mfma_f32_16x16x32_f16(ah[j], bh[n], C[j][n], 0, 0, 0);
        }

        // ---- in-register bias+relu+cvt -> GEMM2 MFMA (no LDS, no barriers) ----
#pragma unroll
        for (int j = 0; j < 4; ++j) {
            int ht = 16 * c0 + wv + 4 * j;
            f32x4 bsv = *(const f32x4*)(bs + 16 * ht + 4 * lq);
            f16x4 af[4];
#pragma unroll
            for (int n = 0; n < 4; n++)
#pragma unroll
                for (int e = 0; e < 4; ++e)
                    af[n][e] = (_Float16)fmaxf(C[j][n][e] + bsv[e], 0.f);
#pragma unroll
            for (int cls = 0; cls < 3; ++cls) {
                f16x4 bf = *(const f16x4*)(W2p + ((size_t)(ht * 3 + cls) * 64 + lane) * 4);
#pragma unroll
                for (int n = 0; n < 4; n++)
                    Lg[n][cls] = __builtin_amdgcn_mfma_f32_16x16x16f16(af[n], bf, Lg[n][cls], 0, 0, 0);
            }
        }
    }

    __syncthreads();                   // barrier 2: all Xs reads done; region becomes Lst
    {
        float* Lw = Lst + (size_t)wv * 64 * LSTR;
#pragma unroll
        for (int n = 0; n < 4; n++)
#pragma unroll
            for (int cls = 0; cls < 3; cls++)
#pragma unroll
                for (int e = 0; e < 4; ++e)
                    Lw[(16 * n + 4 * lq + e) * LSTR + 16 * cls + lr] = Lg[n][cls][e];
    }
    __syncthreads();                   // barrier 3

    // ---- softmax head + fused per-image human argmax (t<64 == wave 0) ----
    if (t < 64) {
        int row = row0 + t;
        float lg[36];
#pragma unroll
        for (int c = 1; c < 36; ++c)
            lg[c] = Lst[t * LSTR + c] + Lst[64 * LSTR + t * LSTR + c]
                  + Lst[128 * LSTR + t * LSTR + c] + Lst[192 * LSTR + t * LSTR + c]
                  + dec2_b[c];
        float m = lg[1];
#pragma unroll
        for (int c = 2; c < 36; ++c) m = fmaxf(m, lg[c]);
        float d[35];
        float s = 0.f;
#pragma unroll
        for (int c = 1; c < 36; ++c) { float e = expf(lg[c] - m); d[c - 1] = e; s += e; }
        float inv = 1.0f / s;
        float* dout = out + (size_t)row * 35;
#pragma unroll
        for (int j = 0; j < 35; ++j) dout[j] = d[j] * inv;

        // per-row argmax over dist cols 1..34 (first-occurrence), label = distcol+1
        float best = -1.f; int bi = 1;
#pragma unroll
        for (int c = 1; c < 35; ++c) {
            float v = d[c] * inv;
            if (v > best) { best = v; bi = c; }
        }

        // block == image: argmax over dist[:,0] across the 64 lanes
        float v0 = d[0] * inv;
        float mv = v0; int mi = t;
#pragma unroll
        for (int off = 32; off > 0; off >>= 1) {
            float ov = __shfl_down(mv, off);
            int   oi = __shfl_down(mi, off);
            if (ov > mv || (ov == mv && oi < mi)) { mv = ov; mi = oi; }
        }
        int human = __shfl(mi, 0);     // local row of the human
        bool isH = (t == human);
        out[(size_t)NROWS * 35 + row] = isH ? v0 : best;
        out[(size_t)NROWS * 36 + row] = isH ? 1.0f : (float)(bi + 1);
        if (t == 0) out[(size_t)NROWS * 37 + blockIdx.x] = (float)(row0 + human);
    }
}

extern "C" void kernel_launch(void* const* d_in, const int* in_sizes, int n_in,
                              void* d_out, int out_size, void* d_ws, size_t ws_size,
                              hipStream_t stream)
{
    (void)in_sizes; (void)n_in; (void)out_size; (void)ws_size;
    const float* distribution = (const float*)d_in[0];
    const float* features     = (const float*)d_in[1];
    const float* boxes        = (const float*)d_in[2];
    const float* obj_embed_W  = (const float*)d_in[3];
    const float* bn4_g        = (const float*)d_in[4];
    const float* bn4_b        = (const float*)d_in[5];
    const float* bn4_m        = (const float*)d_in[6];
    const float* bn4_v        = (const float*)d_in[7];
    const float* pos_W        = (const float*)d_in[8];
    const float* pos_b        = (const float*)d_in[9];
    const float* dec1_W       = (const float*)d_in[10];
    const float* dec1_b       = (const float*)d_in[11];
    const float* bn1k_g       = (const float*)d_in[12];
    const float* bn1k_b       = (const float*)d_in[13];
    const float* bn1k_m       = (const float*)d_in[14];
    const float* bn1k_v       = (const float*)d_in[15];
    const float* dec2_W       = (const float*)d_in[16];
    const float* dec2_b       = (const float*)d_in[17];

    float* out = (float*)d_out;

    // ws layout (~1.01 MB)
    _Float16* W1p  = (_Float16*)d_ws;                      // 1024*384 fp16 (fragment-packed)
    _Float16* W2p  = W1p + (size_t)HID * KP;               // 64*3*256 fp16 (fragment-packed)
    float*    bsv  = (float*)(W2p + (size_t)64 * 3 * 256); // 1024 f32
    float*    Fold = bsv + HID;                            // 35*1024 f32

    k_fold<<<dim3(35, 4), 256, 0, stream>>>(obj_embed_W, dec1_W, Fold);

    int prep_elems = HID * KP + 64 * 3 * 256;              // 442368
    k_prep<<<(prep_elems + 255) / 256, 256, 0, stream>>>(
        Fold, dec1_W, dec1_b, bn1k_g, bn1k_b, bn1k_m, bn1k_v, dec2_W,
        W1p, W2p, bsv);

    k_main<<<BIMG, 256, 0, stream>>>(
        distribution, features, boxes, bn4_g, bn4_b, bn4_m, bn4_v, pos_W, pos_b,
        W1p, W2p, bsv, dec2_b, out);
}